// Round 1
// baseline (1626.769 us; speedup 1.0000x reference)
//
#include <hip/hip_runtime.h>
#include <math.h>

namespace {

constexpr int Bb = 4, Ss = 1024, Dd = 1024, Hh = 16, HDim = 64, Nn = 4096;
constexpr int Mm = Bb * Ss; // 4096

// ---------------------------------------------------------------------------
// Generic fp32 GEMM: C[M,N] = A[M,K] @ W[N,K]^T (+ bias[N])
// Tile 128x128, BK=16, 256 threads, 8x8 micro-tile per thread.
// AFFMAX=true: instead of storing C, reduce max over the 128 rows of the tile
// and write partial[mtile][n]  (no bias).
// Assumes M,N multiples of 128 and K multiple of 16 (true for all our shapes).
// ---------------------------------------------------------------------------
template <bool AFFMAX>
__global__ __launch_bounds__(256) void gemm_kernel(
    const float* __restrict__ A, const float* __restrict__ W,
    const float* __restrict__ bias, float* __restrict__ C, int K, int lda,
    int ldw, int ldc) {
  __shared__ float As[16][128];
  __shared__ float Ws[16][128];
  const int tid = threadIdx.x;
  const int tx = tid & 15, ty = tid >> 4;
  const int n0 = blockIdx.x * 128, m0 = blockIdx.y * 128;
  const int r = tid >> 1, kc = (tid & 1) * 8;
  const float* Arow = A + (size_t)(m0 + r) * lda + kc;
  const float* Wrow = W + (size_t)(n0 + r) * ldw + kc;
  float acc[8][8] = {};
  for (int kt = 0; kt < K; kt += 16) {
    float4 a0 = *(const float4*)(Arow + kt);
    float4 a1 = *(const float4*)(Arow + kt + 4);
    float4 w0 = *(const float4*)(Wrow + kt);
    float4 w1 = *(const float4*)(Wrow + kt + 4);
    __syncthreads();  // previous iteration's LDS reads complete
    As[kc + 0][r] = a0.x; As[kc + 1][r] = a0.y;
    As[kc + 2][r] = a0.z; As[kc + 3][r] = a0.w;
    As[kc + 4][r] = a1.x; As[kc + 5][r] = a1.y;
    As[kc + 6][r] = a1.z; As[kc + 7][r] = a1.w;
    Ws[kc + 0][r] = w0.x; Ws[kc + 1][r] = w0.y;
    Ws[kc + 2][r] = w0.z; Ws[kc + 3][r] = w0.w;
    Ws[kc + 4][r] = w1.x; Ws[kc + 5][r] = w1.y;
    Ws[kc + 6][r] = w1.z; Ws[kc + 7][r] = w1.w;
    __syncthreads();
#pragma unroll
    for (int kk = 0; kk < 16; ++kk) {
      float4 a0r = *(const float4*)&As[kk][ty * 8];
      float4 a1r = *(const float4*)&As[kk][ty * 8 + 4];
      float4 b0r = *(const float4*)&Ws[kk][tx * 8];
      float4 b1r = *(const float4*)&Ws[kk][tx * 8 + 4];
      float av[8] = {a0r.x, a0r.y, a0r.z, a0r.w, a1r.x, a1r.y, a1r.z, a1r.w};
      float bv[8] = {b0r.x, b0r.y, b0r.z, b0r.w, b1r.x, b1r.y, b1r.z, b1r.w};
#pragma unroll
      for (int i = 0; i < 8; ++i)
#pragma unroll
        for (int j = 0; j < 8; ++j)
          acc[i][j] = fmaf(av[i], bv[j], acc[i][j]);
    }
  }
  if constexpr (!AFFMAX) {
#pragma unroll
    for (int i = 0; i < 8; ++i) {
      const int row = m0 + ty * 8 + i;
      float* crow = C + (size_t)row * ldc + n0 + tx * 8;
#pragma unroll
      for (int j = 0; j < 8; ++j) crow[j] = acc[i][j] + bias[n0 + tx * 8 + j];
    }
  } else {
    float cm[8];
#pragma unroll
    for (int j = 0; j < 8; ++j) {
      float m = acc[0][j];
#pragma unroll
      for (int i = 1; i < 8; ++i) m = fmaxf(m, acc[i][j]);
      cm[j] = m;
    }
    __syncthreads();  // done reading As from K-loop
#pragma unroll
    for (int j = 0; j < 8; ++j) As[ty][tx * 8 + j] = cm[j];
    __syncthreads();
    if (tid < 128) {
      float m = As[0][tid];
#pragma unroll
      for (int yy = 1; yy < 16; ++yy) m = fmaxf(m, As[yy][tid]);
      C[(size_t)blockIdx.y * ldc + n0 + tid] = m;  // partial[mtile][n]
    }
  }
}

// ---------------------------------------------------------------------------
// Flash attention, fp32. Grid: (S/64 q-tiles, B*H). Block 256.
// qkv layout [B,S,3D]; head h occupies cols h*64 (q), D+h*64 (k), 2D+h*64 (v).
// Online softmax with 64x64 score tiles. K^T tile and P tile share LDS.
// ---------------------------------------------------------------------------
__global__ __launch_bounds__(256) void attn_kernel(
    const float* __restrict__ qkv, float* __restrict__ ctx) {
  constexpr int LD = 68;
  __shared__ float Qs[64][LD];
  __shared__ float KPs[64][LD];  // K^T [d][kcol] during scores; P [qrow][kcol] during PV
  __shared__ float Vs[64][LD];   // [krow][d]
  const int tid = threadIdx.x;
  const int tx = tid & 15, ty = tid >> 4;
  const int bh = blockIdx.y, b = bh >> 4, h = bh & 15;
  const int q0 = blockIdx.x * 64;
  const size_t rowstride = 3 * Dd;
  const float* qbase = qkv + (size_t)b * Ss * rowstride + h * HDim;
  const float* kbase = qbase + Dd;
  const float* vbase = qbase + 2 * Dd;
  {
    const int r = tid >> 2, c0 = (tid & 3) * 16;
    const float* qr = qbase + (size_t)(q0 + r) * rowstride + c0;
#pragma unroll
    for (int c = 0; c < 16; c += 4)
      *(float4*)&Qs[r][c0 + c] = *(const float4*)(qr + c);
  }
  float O[4][4] = {};
  float mrow[4] = {-INFINITY, -INFINITY, -INFINITY, -INFINITY};
  float lrow[4] = {};
  for (int kt0 = 0; kt0 < Ss; kt0 += 64) {
    const int r = tid >> 2, c0 = (tid & 3) * 16;
    const float* kr = kbase + (size_t)(kt0 + r) * rowstride + c0;
    const float* vr = vbase + (size_t)(kt0 + r) * rowstride + c0;
    float4 kv[4], vv[4];
#pragma unroll
    for (int c = 0; c < 4; ++c) {
      kv[c] = *(const float4*)(kr + c * 4);
      vv[c] = *(const float4*)(vr + c * 4);
    }
    __syncthreads();  // prior PV reads of Vs/KPs done
#pragma unroll
    for (int c = 0; c < 4; ++c) {
      *(float4*)&Vs[r][c0 + 4 * c] = vv[c];
      KPs[c0 + 4 * c + 0][r] = kv[c].x;
      KPs[c0 + 4 * c + 1][r] = kv[c].y;
      KPs[c0 + 4 * c + 2][r] = kv[c].z;
      KPs[c0 + 4 * c + 3][r] = kv[c].w;
    }
    __syncthreads();
    // scores: sc[i][j] = sum_d Q[ty*4+i][d] * K[tx*4+j][d]
    float sc[4][4] = {};
#pragma unroll
    for (int d0 = 0; d0 < HDim; d0 += 4) {
      float4 qa[4];
#pragma unroll
      for (int i = 0; i < 4; ++i) qa[i] = *(const float4*)&Qs[ty * 4 + i][d0];
#pragma unroll
      for (int dd = 0; dd < 4; ++dd) {
        float4 kb = *(const float4*)&KPs[d0 + dd][tx * 4];
#pragma unroll
        for (int i = 0; i < 4; ++i) {
          float q = (dd == 0) ? qa[i].x : (dd == 1) ? qa[i].y
                    : (dd == 2) ? qa[i].z : qa[i].w;
          sc[i][0] = fmaf(q, kb.x, sc[i][0]);
          sc[i][1] = fmaf(q, kb.y, sc[i][1]);
          sc[i][2] = fmaf(q, kb.z, sc[i][2]);
          sc[i][3] = fmaf(q, kb.w, sc[i][3]);
        }
      }
    }
    __syncthreads();  // scores reads of KPs (K^T) done; safe to overwrite with P
    // online softmax update; write P into KPs
#pragma unroll
    for (int i = 0; i < 4; ++i) {
      float s0 = sc[i][0] * 0.125f, s1 = sc[i][1] * 0.125f;
      float s2 = sc[i][2] * 0.125f, s3 = sc[i][3] * 0.125f;
      float tm = fmaxf(fmaxf(s0, s1), fmaxf(s2, s3));
#pragma unroll
      for (int msk = 1; msk < 16; msk <<= 1) tm = fmaxf(tm, __shfl_xor(tm, msk));
      float mnew = fmaxf(mrow[i], tm);
      float p0 = expf(s0 - mnew), p1 = expf(s1 - mnew);
      float p2 = expf(s2 - mnew), p3 = expf(s3 - mnew);
      KPs[ty * 4 + i][tx * 4 + 0] = p0;
      KPs[ty * 4 + i][tx * 4 + 1] = p1;
      KPs[ty * 4 + i][tx * 4 + 2] = p2;
      KPs[ty * 4 + i][tx * 4 + 3] = p3;
      float rs = p0 + p1 + p2 + p3;
#pragma unroll
      for (int msk = 1; msk < 16; msk <<= 1) rs += __shfl_xor(rs, msk);
      float corr = expf(mrow[i] - mnew);
      lrow[i] = lrow[i] * corr + rs;
      mrow[i] = mnew;
      O[i][0] *= corr; O[i][1] *= corr; O[i][2] *= corr; O[i][3] *= corr;
    }
    __syncthreads();
    // PV: O[i][c] += sum_j P[ty*4+i][j] * V[j][tx*4+c]
#pragma unroll
    for (int j0 = 0; j0 < 64; j0 += 4) {
      float4 pa[4];
#pragma unroll
      for (int i = 0; i < 4; ++i) pa[i] = *(const float4*)&KPs[ty * 4 + i][j0];
#pragma unroll
      for (int jj = 0; jj < 4; ++jj) {
        float4 vb = *(const float4*)&Vs[j0 + jj][tx * 4];
#pragma unroll
        for (int i = 0; i < 4; ++i) {
          float p = (jj == 0) ? pa[i].x : (jj == 1) ? pa[i].y
                    : (jj == 2) ? pa[i].z : pa[i].w;
          O[i][0] = fmaf(p, vb.x, O[i][0]);
          O[i][1] = fmaf(p, vb.y, O[i][1]);
          O[i][2] = fmaf(p, vb.z, O[i][2]);
          O[i][3] = fmaf(p, vb.w, O[i][3]);
        }
      }
    }
  }
#pragma unroll
  for (int i = 0; i < 4; ++i) {
    float inv = 1.0f / lrow[i];
    const int srow = q0 + ty * 4 + i;
    float* orow = ctx + ((size_t)(b * Ss + srow)) * Dd + h * HDim + tx * 4;
    orow[0] = O[i][0] * inv;
    orow[1] = O[i][1] * inv;
    orow[2] = O[i][2] * inv;
    orow[3] = O[i][3] * inv;
  }
}

// ---------------------------------------------------------------------------
// Router: per batch, pooled max over 8 partial m-tiles -> logits -> softmax
// -> iterative stable top-k -> idx (as float) + renormalized masked weights.
// Grid: (B). Block 256.
// ---------------------------------------------------------------------------
__global__ __launch_bounds__(256) void router_kernel(
    const float* __restrict__ partial, const float* __restrict__ aff_b,
    const int* __restrict__ kp, float* __restrict__ out, int out_size) {
  __shared__ float lorig[Nn];
  __shared__ float lwork[Nn];
  __shared__ unsigned char flags[Nn];
  __shared__ float rv[4];
  __shared__ int ri[4];
  const int tid = threadIdx.x;
  const int b = blockIdx.x;
  const int kcount = *kp;
  float* idx_out = out;
  float* w_out = out + (out_size - Mm * Dd - Bb * Nn);
  for (int n = tid; n < Nn; n += 256) {
    float m = partial[(size_t)(b * 8) * Nn + n];
#pragma unroll
    for (int t = 1; t < 8; ++t)
      m = fmaxf(m, partial[(size_t)(b * 8 + t) * Nn + n]);
    float lg = (m + aff_b[n]) * 0.5f;  // /TEMPERATURE
    lorig[n] = lg;
    lwork[n] = lg;
    flags[n] = 0;
  }
  __syncthreads();
  // global max
  float gm = -INFINITY;
  for (int c = 0; c < 16; ++c) gm = fmaxf(gm, lorig[c * 256 + tid]);
#pragma unroll
  for (int msk = 1; msk < 64; msk <<= 1) gm = fmaxf(gm, __shfl_xor(gm, msk));
  if ((tid & 63) == 0) rv[tid >> 6] = gm;
  __syncthreads();
  gm = fmaxf(fmaxf(rv[0], rv[1]), fmaxf(rv[2], rv[3]));
  __syncthreads();
  // sum of exp
  float se = 0.f;
  for (int c = 0; c < 16; ++c) se += expf(lorig[c * 256 + tid] - gm);
#pragma unroll
  for (int msk = 1; msk < 64; msk <<= 1) se += __shfl_xor(se, msk);
  if ((tid & 63) == 0) rv[tid >> 6] = se;
  __syncthreads();
  se = rv[0] + rv[1] + rv[2] + rv[3];
  __syncthreads();
  // iterative stable top-k
  float esel = 0.f;
  for (int it = 0; it < kcount; ++it) {
    float v = -INFINITY;
    int bi = 1 << 30;
    for (int c = 0; c < 16; ++c) {
      int n = c * 256 + tid;
      float x = lwork[n];
      if (x > v || (x == v && n < bi)) { v = x; bi = n; }
    }
#pragma unroll
    for (int msk = 1; msk < 64; msk <<= 1) {
      float ov = __shfl_xor(v, msk);
      int oi = __shfl_xor(bi, msk);
      if (ov > v || (ov == v && oi < bi)) { v = ov; bi = oi; }
    }
    if ((tid & 63) == 0) { rv[tid >> 6] = v; ri[tid >> 6] = bi; }
    __syncthreads();
    float bv = rv[0];
    int bidx = ri[0];
#pragma unroll
    for (int w = 1; w < 4; ++w) {
      if (rv[w] > bv || (rv[w] == bv && ri[w] < bidx)) { bv = rv[w]; bidx = ri[w]; }
    }
    if (tid == 0) {
      idx_out[b * kcount + it] = (float)bidx;
      lwork[bidx] = -INFINITY;
      flags[bidx] = 1;
    }
    esel += expf(lorig[bidx] - gm);  // identical in all threads
    __syncthreads();
  }
  const float msum = esel / se;  // sum of selected soft values
  const float wd = msum + 1e-8f;
  for (int n = tid; n < Nn; n += 256) {
    float w = flags[n] ? (expf(lorig[n] - gm) / se) / wd : 0.f;
    w_out[(size_t)b * Nn + n] = w;
  }
}

}  // namespace

extern "C" void kernel_launch(void* const* d_in, const int* in_sizes, int n_in,
                              void* d_out, int out_size, void* d_ws,
                              size_t ws_size, hipStream_t stream) {
  (void)in_sizes; (void)n_in; (void)ws_size;
  const float* x = (const float*)d_in[0];
  const float* in_proj_w = (const float*)d_in[1];
  const float* in_proj_b = (const float*)d_in[2];
  const float* out_w = (const float*)d_in[3];
  const float* out_b = (const float*)d_in[4];
  const float* aff_w = (const float*)d_in[5];
  const float* aff_b = (const float*)d_in[6];
  const int* kp = (const int*)d_in[7];

  float* qkv = (float*)d_ws;                       // [4096, 3072]
  float* ctxws = qkv + (size_t)Mm * 3 * Dd;        // [4096, 1024]
  float* partial = ctxws + (size_t)Mm * Dd;        // [32, 4096]

  float* out = (float*)d_out;
  float* ctx_out = out + ((size_t)out_size - (size_t)Mm * Dd);  // context tail

  // 1) qkv = x @ in_proj_w^T + b
  gemm_kernel<false><<<dim3(3 * Dd / 128, Mm / 128), 256, 0, stream>>>(
      x, in_proj_w, in_proj_b, qkv, Dd, Dd, Dd, 3 * Dd);
  // 2) attention -> ctx (merged heads)
  attn_kernel<<<dim3(Ss / 64, Bb * Hh), 256, 0, stream>>>(qkv, ctxws);
  // 3) context = ctx @ out_w^T + b   (into d_out tail)
  gemm_kernel<false><<<dim3(Dd / 128, Mm / 128), 256, 0, stream>>>(
      ctxws, out_w, out_b, ctx_out, Dd, Dd, Dd, Dd);
  // 4) partial[mtile][n] = max over 128 rows of (context @ aff_w^T)
  gemm_kernel<true><<<dim3(Nn / 128, Mm / 128), 256, 0, stream>>>(
      ctx_out, aff_w, nullptr, partial, Dd, Dd, Dd, Nn);
  // 5) router: pooled max, softmax, top-k, weights
  router_kernel<<<dim3(Bb), 256, 0, stream>>>(partial, aff_b, kp, out, out_size);
}

// Round 2
// 1287.296 us; speedup vs baseline: 1.2637x; 1.2637x over previous
//
#include <hip/hip_runtime.h>
#include <math.h>

namespace {

constexpr int Bb = 4, Ss = 1024, Dd = 1024, Hh = 16, HDim = 64, Nn = 4096;
constexpr int Mm = Bb * Ss; // 4096

// ---------------------------------------------------------------------------
// Generic fp32 GEMM: C[M,N] = A[M,K] @ W[N,K]^T (+ bias[N])
// Tile 128x128, BK=16, 256 threads, 8x8 micro-tile per thread.
// AFFMAX=true: instead of storing C, reduce max over the 128 rows of the tile
// and write partial[mtile][n]  (no bias).
// ---------------------------------------------------------------------------
template <bool AFFMAX>
__global__ __launch_bounds__(256) void gemm_kernel(
    const float* __restrict__ A, const float* __restrict__ W,
    const float* __restrict__ bias, float* __restrict__ C, int K, int lda,
    int ldw, int ldc) {
  __shared__ float As[16][128];
  __shared__ float Ws[16][128];
  const int tid = threadIdx.x;
  const int tx = tid & 15, ty = tid >> 4;
  const int n0 = blockIdx.x * 128, m0 = blockIdx.y * 128;
  const int r = tid >> 1, kc = (tid & 1) * 8;
  const float* Arow = A + (size_t)(m0 + r) * lda + kc;
  const float* Wrow = W + (size_t)(n0 + r) * ldw + kc;
  float acc[8][8] = {};
  for (int kt = 0; kt < K; kt += 16) {
    float4 a0 = *(const float4*)(Arow + kt);
    float4 a1 = *(const float4*)(Arow + kt + 4);
    float4 w0 = *(const float4*)(Wrow + kt);
    float4 w1 = *(const float4*)(Wrow + kt + 4);
    __syncthreads();  // previous iteration's LDS reads complete
    As[kc + 0][r] = a0.x; As[kc + 1][r] = a0.y;
    As[kc + 2][r] = a0.z; As[kc + 3][r] = a0.w;
    As[kc + 4][r] = a1.x; As[kc + 5][r] = a1.y;
    As[kc + 6][r] = a1.z; As[kc + 7][r] = a1.w;
    Ws[kc + 0][r] = w0.x; Ws[kc + 1][r] = w0.y;
    Ws[kc + 2][r] = w0.z; Ws[kc + 3][r] = w0.w;
    Ws[kc + 4][r] = w1.x; Ws[kc + 5][r] = w1.y;
    Ws[kc + 6][r] = w1.z; Ws[kc + 7][r] = w1.w;
    __syncthreads();
#pragma unroll
    for (int kk = 0; kk < 16; ++kk) {
      float4 a0r = *(const float4*)&As[kk][ty * 8];
      float4 a1r = *(const float4*)&As[kk][ty * 8 + 4];
      float4 b0r = *(const float4*)&Ws[kk][tx * 8];
      float4 b1r = *(const float4*)&Ws[kk][tx * 8 + 4];
      float av[8] = {a0r.x, a0r.y, a0r.z, a0r.w, a1r.x, a1r.y, a1r.z, a1r.w};
      float bv[8] = {b0r.x, b0r.y, b0r.z, b0r.w, b1r.x, b1r.y, b1r.z, b1r.w};
#pragma unroll
      for (int i = 0; i < 8; ++i)
#pragma unroll
        for (int j = 0; j < 8; ++j)
          acc[i][j] = fmaf(av[i], bv[j], acc[i][j]);
    }
  }
  if constexpr (!AFFMAX) {
#pragma unroll
    for (int i = 0; i < 8; ++i) {
      const int row = m0 + ty * 8 + i;
      float* crow = C + (size_t)row * ldc + n0 + tx * 8;
#pragma unroll
      for (int j = 0; j < 8; ++j) crow[j] = acc[i][j] + bias[n0 + tx * 8 + j];
    }
  } else {
    float cm[8];
#pragma unroll
    for (int j = 0; j < 8; ++j) {
      float m = acc[0][j];
#pragma unroll
      for (int i = 1; i < 8; ++i) m = fmaxf(m, acc[i][j]);
      cm[j] = m;
    }
    __syncthreads();  // done reading As from K-loop
#pragma unroll
    for (int j = 0; j < 8; ++j) As[ty][tx * 8 + j] = cm[j];
    __syncthreads();
    if (tid < 128) {
      float m = As[0][tid];
#pragma unroll
      for (int yy = 1; yy < 16; ++yy) m = fmaxf(m, As[yy][tid]);
      C[(size_t)blockIdx.y * ldc + n0 + tid] = m;  // partial[mtile][n]
    }
  }
}

// ---------------------------------------------------------------------------
// Flash attention, fp32. Grid: (S/64 q-tiles, B*H). Block 256.
// ---------------------------------------------------------------------------
__global__ __launch_bounds__(256) void attn_kernel(
    const float* __restrict__ qkv, float* __restrict__ ctx) {
  constexpr int LD = 68;
  __shared__ float Qs[64][LD];
  __shared__ float KPs[64][LD];  // K^T during scores; P during PV
  __shared__ float Vs[64][LD];   // [krow][d]
  const int tid = threadIdx.x;
  const int tx = tid & 15, ty = tid >> 4;
  const int bh = blockIdx.y, b = bh >> 4, h = bh & 15;
  const int q0 = blockIdx.x * 64;
  const size_t rowstride = 3 * Dd;
  const float* qbase = qkv + (size_t)b * Ss * rowstride + h * HDim;
  const float* kbase = qbase + Dd;
  const float* vbase = qbase + 2 * Dd;
  {
    const int r = tid >> 2, c0 = (tid & 3) * 16;
    const float* qr = qbase + (size_t)(q0 + r) * rowstride + c0;
#pragma unroll
    for (int c = 0; c < 16; c += 4)
      *(float4*)&Qs[r][c0 + c] = *(const float4*)(qr + c);
  }
  float O[4][4] = {};
  float mrow[4] = {-INFINITY, -INFINITY, -INFINITY, -INFINITY};
  float lrow[4] = {};
  for (int kt0 = 0; kt0 < Ss; kt0 += 64) {
    const int r = tid >> 2, c0 = (tid & 3) * 16;
    const float* kr = kbase + (size_t)(kt0 + r) * rowstride + c0;
    const float* vr = vbase + (size_t)(kt0 + r) * rowstride + c0;
    float4 kv[4], vv[4];
#pragma unroll
    for (int c = 0; c < 4; ++c) {
      kv[c] = *(const float4*)(kr + c * 4);
      vv[c] = *(const float4*)(vr + c * 4);
    }
    __syncthreads();  // prior PV reads of Vs/KPs done
#pragma unroll
    for (int c = 0; c < 4; ++c) {
      *(float4*)&Vs[r][c0 + 4 * c] = vv[c];
      KPs[c0 + 4 * c + 0][r] = kv[c].x;
      KPs[c0 + 4 * c + 1][r] = kv[c].y;
      KPs[c0 + 4 * c + 2][r] = kv[c].z;
      KPs[c0 + 4 * c + 3][r] = kv[c].w;
    }
    __syncthreads();
    float sc[4][4] = {};
#pragma unroll
    for (int d0 = 0; d0 < HDim; d0 += 4) {
      float4 qa[4];
#pragma unroll
      for (int i = 0; i < 4; ++i) qa[i] = *(const float4*)&Qs[ty * 4 + i][d0];
#pragma unroll
      for (int dd = 0; dd < 4; ++dd) {
        float4 kb = *(const float4*)&KPs[d0 + dd][tx * 4];
#pragma unroll
        for (int i = 0; i < 4; ++i) {
          float q = (dd == 0) ? qa[i].x : (dd == 1) ? qa[i].y
                    : (dd == 2) ? qa[i].z : qa[i].w;
          sc[i][0] = fmaf(q, kb.x, sc[i][0]);
          sc[i][1] = fmaf(q, kb.y, sc[i][1]);
          sc[i][2] = fmaf(q, kb.z, sc[i][2]);
          sc[i][3] = fmaf(q, kb.w, sc[i][3]);
        }
      }
    }
    __syncthreads();  // K^T reads done; safe to overwrite with P
#pragma unroll
    for (int i = 0; i < 4; ++i) {
      float s0 = sc[i][0] * 0.125f, s1 = sc[i][1] * 0.125f;
      float s2 = sc[i][2] * 0.125f, s3 = sc[i][3] * 0.125f;
      float tm = fmaxf(fmaxf(s0, s1), fmaxf(s2, s3));
#pragma unroll
      for (int msk = 1; msk < 16; msk <<= 1) tm = fmaxf(tm, __shfl_xor(tm, msk));
      float mnew = fmaxf(mrow[i], tm);
      float p0 = expf(s0 - mnew), p1 = expf(s1 - mnew);
      float p2 = expf(s2 - mnew), p3 = expf(s3 - mnew);
      KPs[ty * 4 + i][tx * 4 + 0] = p0;
      KPs[ty * 4 + i][tx * 4 + 1] = p1;
      KPs[ty * 4 + i][tx * 4 + 2] = p2;
      KPs[ty * 4 + i][tx * 4 + 3] = p3;
      float rs = p0 + p1 + p2 + p3;
#pragma unroll
      for (int msk = 1; msk < 16; msk <<= 1) rs += __shfl_xor(rs, msk);
      float corr = expf(mrow[i] - mnew);
      lrow[i] = lrow[i] * corr + rs;
      mrow[i] = mnew;
      O[i][0] *= corr; O[i][1] *= corr; O[i][2] *= corr; O[i][3] *= corr;
    }
    __syncthreads();
#pragma unroll
    for (int j0 = 0; j0 < 64; j0 += 4) {
      float4 pa[4];
#pragma unroll
      for (int i = 0; i < 4; ++i) pa[i] = *(const float4*)&KPs[ty * 4 + i][j0];
#pragma unroll
      for (int jj = 0; jj < 4; ++jj) {
        float4 vb = *(const float4*)&Vs[j0 + jj][tx * 4];
#pragma unroll
        for (int i = 0; i < 4; ++i) {
          float p = (jj == 0) ? pa[i].x : (jj == 1) ? pa[i].y
                    : (jj == 2) ? pa[i].z : pa[i].w;
          O[i][0] = fmaf(p, vb.x, O[i][0]);
          O[i][1] = fmaf(p, vb.y, O[i][1]);
          O[i][2] = fmaf(p, vb.z, O[i][2]);
          O[i][3] = fmaf(p, vb.w, O[i][3]);
        }
      }
    }
  }
#pragma unroll
  for (int i = 0; i < 4; ++i) {
    float inv = 1.0f / lrow[i];
    const int srow = q0 + ty * 4 + i;
    float* orow = ctx + ((size_t)(b * Ss + srow)) * Dd + h * HDim + tx * 4;
    orow[0] = O[i][0] * inv;
    orow[1] = O[i][1] * inv;
    orow[2] = O[i][2] * inv;
    orow[3] = O[i][3] * inv;
  }
}

// ---------------------------------------------------------------------------
// Router v2: bitonic full-sort of packed u64 keys replaces the 256-iteration
// serial argmax (was ~500us @ 0.2% VALUBusy; sort is ~78 passes * 8 pairs).
// key = sortable(value) << 32 | (Nn-1-n): descending u64 order == descending
// value with ascending index tiebreak == jax.lax.top_k stable order, exactly.
// Grid: (B). Block 256.
// ---------------------------------------------------------------------------
__device__ inline unsigned int f2s(float f) {
  unsigned int u = __float_as_uint(f);
  return (u >> 31) ? ~u : (u | 0x80000000u);
}
__device__ inline float s2f(unsigned int s) {
  unsigned int u = (s >> 31) ? (s & 0x7fffffffu) : ~s;
  return __uint_as_float(u);
}

__global__ __launch_bounds__(256) void router_kernel(
    const float* __restrict__ partial, const float* __restrict__ aff_b,
    const int* __restrict__ kp, float* __restrict__ out, int out_size) {
  __shared__ unsigned long long keys[Nn];   // 32 KB
  __shared__ float lorig[Nn];               // 16 KB
  __shared__ float rv[4];
  const int tid = threadIdx.x;
  const int b = blockIdx.x;
  const int kcount = *kp;
  float* idx_out = out;
  float* w_out = out + (out_size - Mm * Dd - Bb * Nn);
  // logits
  for (int n = tid; n < Nn; n += 256) {
    float m = partial[(size_t)(b * 8) * Nn + n];
#pragma unroll
    for (int t = 1; t < 8; ++t)
      m = fmaxf(m, partial[(size_t)(b * 8 + t) * Nn + n]);
    float lg = (m + aff_b[n]) * 0.5f;  // /TEMPERATURE
    lorig[n] = lg;
    keys[n] = ((unsigned long long)f2s(lg) << 32) |
              (unsigned int)(Nn - 1 - n);
  }
  __syncthreads();
  // bitonic sort, descending
  for (int kk = 2; kk <= Nn; kk <<= 1) {
    for (int j = kk >> 1; j > 0; j >>= 1) {
#pragma unroll 4
      for (int t = tid; t < Nn / 2; t += 256) {
        const int i = 2 * j * (t / j) + (t % j);
        const int p = i + j;
        const bool desc = ((i & kk) == 0);
        unsigned long long a = keys[i], c = keys[p];
        if (desc ? (a < c) : (a > c)) { keys[i] = c; keys[p] = a; }
      }
      __syncthreads();
    }
  }
  // gm = max logit (bit-exact decode of keys[0])
  const float gm = s2f((unsigned int)(keys[0] >> 32));
  // se = sum exp(l - gm)
  float se = 0.f;
  for (int n = tid; n < Nn; n += 256) se += expf(lorig[n] - gm);
#pragma unroll
  for (int msk = 1; msk < 64; msk <<= 1) se += __shfl_xor(se, msk);
  if ((tid & 63) == 0) rv[tid >> 6] = se;
  __syncthreads();
  se = rv[0] + rv[1] + rv[2] + rv[3];
  __syncthreads();
  // esel = sum of exp over the selected (top-kcount) set
  float es = 0.f;
  for (int p = tid; p < kcount; p += 256)
    es += expf(s2f((unsigned int)(keys[p] >> 32)) - gm);
#pragma unroll
  for (int msk = 1; msk < 64; msk <<= 1) es += __shfl_xor(es, msk);
  if ((tid & 63) == 0) rv[tid >> 6] = es;
  __syncthreads();
  es = rv[0] + rv[1] + rv[2] + rv[3];
  const float wd = es / se + 1e-8f;
  // zero the weight row, then scatter selected weights
  for (int n = tid; n < Nn; n += 256) w_out[(size_t)b * Nn + n] = 0.f;
  __syncthreads();
  for (int p = tid; p < kcount; p += 256) {
    const unsigned long long kkey = keys[p];
    const int n = Nn - 1 - (int)(kkey & 0xffffffffu);
    const float val = s2f((unsigned int)(kkey >> 32));
    idx_out[b * kcount + p] = (float)n;
    w_out[(size_t)b * Nn + n] = (expf(val - gm) / se) / wd;
  }
}

}  // namespace

extern "C" void kernel_launch(void* const* d_in, const int* in_sizes, int n_in,
                              void* d_out, int out_size, void* d_ws,
                              size_t ws_size, hipStream_t stream) {
  (void)in_sizes; (void)n_in; (void)ws_size;
  const float* x = (const float*)d_in[0];
  const float* in_proj_w = (const float*)d_in[1];
  const float* in_proj_b = (const float*)d_in[2];
  const float* out_w = (const float*)d_in[3];
  const float* out_b = (const float*)d_in[4];
  const float* aff_w = (const float*)d_in[5];
  const float* aff_b = (const float*)d_in[6];
  const int* kp = (const int*)d_in[7];

  float* qkv = (float*)d_ws;                       // [4096, 3072]
  float* ctxws = qkv + (size_t)Mm * 3 * Dd;        // [4096, 1024]
  float* partial = ctxws + (size_t)Mm * Dd;        // [32, 4096]

  float* out = (float*)d_out;
  float* ctx_out = out + ((size_t)out_size - (size_t)Mm * Dd);  // context tail

  gemm_kernel<false><<<dim3(3 * Dd / 128, Mm / 128), 256, 0, stream>>>(
      x, in_proj_w, in_proj_b, qkv, Dd, Dd, Dd, 3 * Dd);
  attn_kernel<<<dim3(Ss / 64, Bb * Hh), 256, 0, stream>>>(qkv, ctxws);
  gemm_kernel<false><<<dim3(Dd / 128, Mm / 128), 256, 0, stream>>>(
      ctxws, out_w, out_b, ctx_out, Dd, Dd, Dd, Dd);
  gemm_kernel<true><<<dim3(Nn / 128, Mm / 128), 256, 0, stream>>>(
      ctx_out, aff_w, nullptr, partial, Dd, Dd, Dd, Nn);
  router_kernel<<<dim3(Bb), 256, 0, stream>>>(partial, aff_b, kp, out, out_size);
}